// Round 17
// baseline (69.833 us; speedup 1.0000x reference)
//
#include <hip/hip_runtime.h>
#include <hip/hip_bf16.h>

// GraphLSTM fused kernel for MI355X — R17 = R15 read path + R16 write path.
// R16's regression isolated to the scattered x gather (64 lines/wave/edge vs
// xt's 4): restore the prep transpose. Keep unique-slot res[e*8+b] stores
// (no atomics, no partial zeroing) + binary-search CSR reduce (dst_idx is
// sorted in [MN,E), self edges are e==n).

#define MN 1024
#define BB 8

__device__ __forceinline__ float fsig(float x) {
    return __builtin_amdgcn_rcpf(1.0f + __expf(-x));
}
__device__ __forceinline__ float ftanh(float x) {
    float t = fminf(fmaxf(2.0f * x, -30.0f), 30.0f);   // avoid inf/inf
    float e = __expf(t);
    return (e - 1.0f) * __builtin_amdgcn_rcpf(e + 1.0f);
}
__device__ __forceinline__ float rl(float v, int idx) {
    return __int_as_float(__builtin_amdgcn_readlane(__float_as_int(v), idx));
}

// Prep: transpose x (B,D,MN) -> xt (MN,B,D). Nothing else.
__global__ void prep_kernel(const float* __restrict__ x,
                            float* __restrict__ xt) {
    int tid = blockIdx.x * 256 + threadIdx.x;   // 65536 threads
    int mn = tid >> 6;
    int b  = (tid >> 3) & 7;
    int d  = tid & 7;
    xt[tid] = x[b * (8 * MN) + d * MN + mn];
}

struct WRegs {
    float4 wi0, wi1, wg0, wg1, wo0, wo1;   // 24 VGPR
    float  bI, bG, bO;                     // 3 VGPR (pairs combined at load)
};

__device__ __forceinline__ void loadW(WRegs& r, int e, int lane,
        const float* __restrict__ W, const float* __restrict__ b_ih,
        const float* __restrict__ b_hh) {
    const float* We = W + (size_t)e * 2048 + lane * 8;
    r.wi0 = *(const float4*)(We);
    r.wi1 = *(const float4*)(We + 4);
    r.wg0 = *(const float4*)(We + 1024);
    r.wg1 = *(const float4*)(We + 1028);
    r.wo0 = *(const float4*)(We + 1536);
    r.wo1 = *(const float4*)(We + 1540);
    const float* bi = b_ih + (size_t)e * 256 + lane;
    const float* bh = b_hh + (size_t)e * 256 + lane;
    r.bI = bi[0]   + bh[0];
    r.bG = bi[128] + bh[128];
    r.bO = bi[192] + bh[192];
}

// Compute one edge; fold over lanes; store 8 batch values to res[e*8+0..7].
__device__ __forceinline__ void computeEdge(const WRegs& r, float xreg,
        int e, float ew, float cw, float* __restrict__ res, int lane) {
    float s[BB];
#pragma unroll
    for (int b = 0; b < BB; ++b) {
        float x0 = rl(xreg, b * 8 + 0), x1 = rl(xreg, b * 8 + 1);
        float x2 = rl(xreg, b * 8 + 2), x3 = rl(xreg, b * 8 + 3);
        float x4 = rl(xreg, b * 8 + 4), x5 = rl(xreg, b * 8 + 5);
        float x6 = rl(xreg, b * 8 + 6), x7 = rl(xreg, b * 8 + 7);
        float pi = r.bI, pg = r.bG, po = r.bO;
        pi = fmaf(r.wi0.x, x0, pi); pg = fmaf(r.wg0.x, x0, pg); po = fmaf(r.wo0.x, x0, po);
        pi = fmaf(r.wi0.y, x1, pi); pg = fmaf(r.wg0.y, x1, pg); po = fmaf(r.wo0.y, x1, po);
        pi = fmaf(r.wi0.z, x2, pi); pg = fmaf(r.wg0.z, x2, pg); po = fmaf(r.wo0.z, x2, po);
        pi = fmaf(r.wi0.w, x3, pi); pg = fmaf(r.wg0.w, x3, pg); po = fmaf(r.wo0.w, x3, po);
        pi = fmaf(r.wi1.x, x4, pi); pg = fmaf(r.wg1.x, x4, pg); po = fmaf(r.wo1.x, x4, po);
        pi = fmaf(r.wi1.y, x5, pi); pg = fmaf(r.wg1.y, x5, pg); po = fmaf(r.wo1.y, x5, po);
        pi = fmaf(r.wi1.z, x6, pi); pg = fmaf(r.wg1.z, x6, pg); po = fmaf(r.wo1.z, x6, po);
        pi = fmaf(r.wi1.w, x7, pi); pg = fmaf(r.wg1.w, x7, pg); po = fmaf(r.wo1.w, x7, po);
        float c = fsig(pi) * ftanh(pg);
        float h = fsig(po) * ftanh(c);
        s[b] = cw * h;
    }
    // Batch-folding reduction over 64 lanes (Σ_h), 10 shuffles total.
    float u[4];
#pragma unroll
    for (int k = 0; k < 4; ++k) {
        float keep = (lane & 32) ? s[k + 4] : s[k];
        float send = (lane & 32) ? s[k]     : s[k + 4];
        u[k] = keep + __shfl_xor(send, 32, 64);
    }
    float v[2];
#pragma unroll
    for (int k = 0; k < 2; ++k) {
        float keep = (lane & 16) ? u[k + 2] : u[k];
        float send = (lane & 16) ? u[k]     : u[k + 2];
        v[k] = keep + __shfl_xor(send, 16, 64);
    }
    float keep = (lane & 8) ? v[1] : v[0];
    float send = (lane & 8) ? v[0] : v[1];
    float t = keep + __shfl_xor(send, 8, 64);
    t += __shfl_xor(t, 4, 64);
    t += __shfl_xor(t, 2, 64);
    t += __shfl_xor(t, 1, 64);
    if ((lane & 7) == 0) {
        int b = lane >> 3;
        res[e * BB + b] = ew * t;   // unique slot: plain store, no conflict
    }
}

__global__ __launch_bounds__(256, 8) void edge_kernel(
        const float* __restrict__ xt,      // (MN, B, D)
        const float* __restrict__ edge_w,  // (E)
        const float* __restrict__ W,       // (E, 256, 8)
        const float* __restrict__ b_ih,    // (E, 256)
        const float* __restrict__ b_hh,    // (E, 256)
        const float* __restrict__ conv_w,  // (1, 64)
        const int*   __restrict__ src_idx,
        float* __restrict__ res,           // (E, 8) unique slots
        int E) {
    int lane = threadIdx.x & 63;
    int nw = gridDim.x * 4;
    int wid = blockIdx.x * 4 + (threadIdx.x >> 6);
    int e = __builtin_amdgcn_readfirstlane(wid);
    if (e >= E) return;
    float cw = conv_w[lane];

    int   srcC = src_idx[e];
    float ewC  = edge_w[e];

    while (true) {
        int eN = e + nw;
        bool hasN = (eN < E);
        int srcN = 0; float ewN = 0.0f;
        if (hasN) { srcN = src_idx[eN]; ewN = edge_w[eN]; }

        // Current edge burst + compute (8 waves/SIMD hide the wait).
        WRegs A;
        loadW(A, e, lane, W, b_ih, b_hh);
        float xA = xt[(size_t)srcC * 64 + lane];   // 256B contiguous wave read
        computeEdge(A, xA, e, ewC, cw, res, lane);

        if (!hasN) break;
        e = eN; srcC = srcN; ewC = ewN;
    }
}

// Reduce: thread (n,b) sums self-edge + the contiguous dst-run [lo,hi) found
// by binary search in the sorted dst range [MN, E); adds conv_b.
__global__ void reduce_kernel(const float* __restrict__ res,
                              const int* __restrict__ dst_idx,
                              const float* __restrict__ conv_b,
                              float* __restrict__ out, int E) {
    int tid = blockIdx.x * 256 + threadIdx.x;   // 8192 threads
    int n = tid >> 3;
    int b = tid & 7;
    int l = MN, r = E;
    while (l < r) { int m = (l + r) >> 1; if (dst_idx[m] < n) l = m + 1; else r = m; }
    int lo = l;
    r = E;
    while (l < r) { int m = (l + r) >> 1; if (dst_idx[m] < n + 1) l = m + 1; else r = m; }
    int hi = l;
    float s = conv_b[0] + res[n * BB + b];      // self edge e == n
    for (int e = lo; e < hi; ++e) s += res[e * BB + b];
    out[b * MN + n] = s;
}

extern "C" void kernel_launch(void* const* d_in, const int* in_sizes, int n_in,
                              void* d_out, int out_size, void* d_ws, size_t ws_size,
                              hipStream_t stream) {
    const float* x      = (const float*)d_in[0];
    const float* edge_w = (const float*)d_in[1];
    const float* W_ih   = (const float*)d_in[2];
    const float* b_ih   = (const float*)d_in[3];
    const float* b_hh   = (const float*)d_in[4];
    const float* conv_w = (const float*)d_in[5];
    const float* conv_b = (const float*)d_in[6];
    const int* src_idx  = (const int*)d_in[7];
    const int* dst_idx  = (const int*)d_in[8];
    int E = in_sizes[1];

    float* xt  = (float*)d_ws;              // 65536 floats = 256 KB
    float* res = (float*)d_ws + 65536;      // E*8 floats ~= 1.1 MB
    float* out = (float*)d_out;             // 8192 floats

    prep_kernel<<<256, 256, 0, stream>>>(x, xt);

    // 2048 blocks = 8/CU resident = 32 waves/CU.
    edge_kernel<<<2048, 256, 0, stream>>>(xt, edge_w, W_ih, b_ih, b_hh,
                                          conv_w, src_idx, res, E);

    reduce_kernel<<<32, 256, 0, stream>>>(res, dst_idx, conv_b, out, E);
}

// Round 18
// 59.383 us; speedup vs baseline: 1.1760x; 1.1760x over previous
//
#include <hip/hip_runtime.h>
#include <hip/hip_bf16.h>

// GraphLSTM fused kernel for MI355X — R18 = R15 (best, 56.9us) + balanced grid.
// R16/R17 falsified the unique-slot/CSR-reduce path (worse than spread
// atomics). R15 core restored exactly: xt transpose + x32-privatized atomics
// + flat reduce, single WRegs (spill-proof), lb(256,8), idx prefetch 1 ahead.
// Only change: grid computed at runtime so each wave gets exactly ~5 edges
// (waves = ceil(E/5)) -> removes the 4.13-edges/wave tail imbalance while
// keeping ~26 waves/CU (TLP-saturated region per R14->R15).

#define MN 1024
#define BB 8
#define NCOPY 32

__device__ __forceinline__ float fsig(float x) {
    return __builtin_amdgcn_rcpf(1.0f + __expf(-x));
}
__device__ __forceinline__ float ftanh(float x) {
    float t = fminf(fmaxf(2.0f * x, -30.0f), 30.0f);   // avoid inf/inf
    float e = __expf(t);
    return (e - 1.0f) * __builtin_amdgcn_rcpf(e + 1.0f);
}
__device__ __forceinline__ float rl(float v, int idx) {
    return __int_as_float(__builtin_amdgcn_readlane(__float_as_int(v), idx));
}

// Prep: transpose x (B,D,MN) -> xt (MN,B,D); zero the 32 partial buffers.
__global__ void prep_kernel(const float* __restrict__ x,
                            float* __restrict__ xt,
                            float* __restrict__ partial) {
    int tid = blockIdx.x * 256 + threadIdx.x;   // 65536 threads
    if (tid < MN * BB * 8) {
        int mn = tid >> 6;
        int b  = (tid >> 3) & 7;
        int d  = tid & 7;
        xt[tid] = x[b * (8 * MN) + d * MN + mn];
    }
    // Zero 32 x 8192 floats (4 per thread), every launch (replay-safe).
    float4* p4 = (float4*)partial;
    p4[tid] = make_float4(0.f, 0.f, 0.f, 0.f);
}

// Reduce: out[t] = conv_b + sum_k partial[k][t].
__global__ void reduce_kernel(const float* __restrict__ partial,
                              const float* __restrict__ conv_b,
                              float* __restrict__ out) {
    int tid = blockIdx.x * 256 + threadIdx.x;   // 8192 threads
    float s = conv_b[0];
#pragma unroll
    for (int k = 0; k < NCOPY; ++k) s += partial[k * (BB * MN) + tid];
    out[tid] = s;
}

struct WRegs {
    float4 wi0, wi1, wg0, wg1, wo0, wo1;   // 24 VGPR
    float  bI, bG, bO;                     // 3 VGPR (pairs combined at load)
};

__device__ __forceinline__ void loadW(WRegs& r, int e, int lane,
        const float* __restrict__ W, const float* __restrict__ b_ih,
        const float* __restrict__ b_hh) {
    const float* We = W + (size_t)e * 2048 + lane * 8;
    r.wi0 = *(const float4*)(We);
    r.wi1 = *(const float4*)(We + 4);
    r.wg0 = *(const float4*)(We + 1024);
    r.wg1 = *(const float4*)(We + 1028);
    r.wo0 = *(const float4*)(We + 1536);
    r.wo1 = *(const float4*)(We + 1540);
    const float* bi = b_ih + (size_t)e * 256 + lane;
    const float* bh = b_hh + (size_t)e * 256 + lane;
    r.bI = bi[0]   + bh[0];
    r.bG = bi[128] + bh[128];
    r.bO = bi[192] + bh[192];
}

__device__ __forceinline__ void computeEdge(const WRegs& r, float xreg,
        int dst, float ew, float cw, float* __restrict__ pout, int lane) {
    float s[BB];
#pragma unroll
    for (int b = 0; b < BB; ++b) {
        float x0 = rl(xreg, b * 8 + 0), x1 = rl(xreg, b * 8 + 1);
        float x2 = rl(xreg, b * 8 + 2), x3 = rl(xreg, b * 8 + 3);
        float x4 = rl(xreg, b * 8 + 4), x5 = rl(xreg, b * 8 + 5);
        float x6 = rl(xreg, b * 8 + 6), x7 = rl(xreg, b * 8 + 7);
        float pi = r.bI, pg = r.bG, po = r.bO;
        pi = fmaf(r.wi0.x, x0, pi); pg = fmaf(r.wg0.x, x0, pg); po = fmaf(r.wo0.x, x0, po);
        pi = fmaf(r.wi0.y, x1, pi); pg = fmaf(r.wg0.y, x1, pg); po = fmaf(r.wo0.y, x1, po);
        pi = fmaf(r.wi0.z, x2, pi); pg = fmaf(r.wg0.z, x2, pg); po = fmaf(r.wo0.z, x2, po);
        pi = fmaf(r.wi0.w, x3, pi); pg = fmaf(r.wg0.w, x3, pg); po = fmaf(r.wo0.w, x3, po);
        pi = fmaf(r.wi1.x, x4, pi); pg = fmaf(r.wg1.x, x4, pg); po = fmaf(r.wo1.x, x4, po);
        pi = fmaf(r.wi1.y, x5, pi); pg = fmaf(r.wg1.y, x5, pg); po = fmaf(r.wo1.y, x5, po);
        pi = fmaf(r.wi1.z, x6, pi); pg = fmaf(r.wg1.z, x6, pg); po = fmaf(r.wo1.z, x6, po);
        pi = fmaf(r.wi1.w, x7, pi); pg = fmaf(r.wg1.w, x7, pg); po = fmaf(r.wo1.w, x7, po);
        float c = fsig(pi) * ftanh(pg);
        float h = fsig(po) * ftanh(c);
        s[b] = cw * h;
    }
    // Batch-folding reduction over 64 lanes (Σ_h), 10 shuffles total.
    float u[4];
#pragma unroll
    for (int k = 0; k < 4; ++k) {
        float keep = (lane & 32) ? s[k + 4] : s[k];
        float send = (lane & 32) ? s[k]     : s[k + 4];
        u[k] = keep + __shfl_xor(send, 32, 64);
    }
    float v[2];
#pragma unroll
    for (int k = 0; k < 2; ++k) {
        float keep = (lane & 16) ? u[k + 2] : u[k];
        float send = (lane & 16) ? u[k]     : u[k + 2];
        v[k] = keep + __shfl_xor(send, 16, 64);
    }
    float keep = (lane & 8) ? v[1] : v[0];
    float send = (lane & 8) ? v[0] : v[1];
    float t = keep + __shfl_xor(send, 8, 64);
    t += __shfl_xor(t, 4, 64);
    t += __shfl_xor(t, 2, 64);
    t += __shfl_xor(t, 1, 64);
    if ((lane & 7) == 0) {
        int b = lane >> 3;
        atomicAdd(pout + b * MN + dst, ew * t);
    }
}

__global__ __launch_bounds__(256, 8) void edge_kernel(
        const float* __restrict__ xt,      // (MN, B, D)
        const float* __restrict__ edge_w,  // (E)
        const float* __restrict__ W,       // (E, 256, 8)
        const float* __restrict__ b_ih,    // (E, 256)
        const float* __restrict__ b_hh,    // (E, 256)
        const float* __restrict__ conv_w,  // (1, 64)
        const int*   __restrict__ src_idx,
        const int*   __restrict__ dst_idx,
        float* __restrict__ partial,       // (NCOPY, B, MN) zeroed by prep
        int E) {
    int lane = threadIdx.x & 63;
    int nw = gridDim.x * 4;
    int wid = blockIdx.x * 4 + (threadIdx.x >> 6);
    int e = __builtin_amdgcn_readfirstlane(wid);
    if (e >= E) return;
    float cw = conv_w[lane];
    float* pout = partial + (size_t)(wid & (NCOPY - 1)) * (BB * MN);

    int   srcC = src_idx[e], dstC = dst_idx[e];
    float ewC  = edge_w[e];

    while (true) {
        int eN = e + nw;
        bool hasN = (eN < E);
        // idx for next edge (s_load; hidden under this edge's load+compute).
        int srcN = 0, dstN = 0; float ewN = 0.0f;
        if (hasN) { srcN = src_idx[eN]; dstN = dst_idx[eN]; ewN = edge_w[eN]; }

        // Current edge burst + compute (8 waves/SIMD hide the wait).
        WRegs A;
        loadW(A, e, lane, W, b_ih, b_hh);
        float xA = xt[(size_t)srcC * 64 + lane];
        computeEdge(A, xA, dstC, ewC, cw, pout, lane);

        if (!hasN) break;
        e = eN; srcC = srcN; dstC = dstN; ewC = ewN;
    }
}

extern "C" void kernel_launch(void* const* d_in, const int* in_sizes, int n_in,
                              void* d_out, int out_size, void* d_ws, size_t ws_size,
                              hipStream_t stream) {
    const float* x      = (const float*)d_in[0];
    const float* edge_w = (const float*)d_in[1];
    const float* W_ih   = (const float*)d_in[2];
    const float* b_ih   = (const float*)d_in[3];
    const float* b_hh   = (const float*)d_in[4];
    const float* conv_w = (const float*)d_in[5];
    const float* conv_b = (const float*)d_in[6];
    const int* src_idx  = (const int*)d_in[7];
    const int* dst_idx  = (const int*)d_in[8];
    int E = in_sizes[1];

    float* xt      = (float*)d_ws;             // 65536 floats = 256 KB
    float* partial = (float*)d_ws + 65536;     // 32 x 8192 floats = 1 MB
    float* out     = (float*)d_out;            // 8192 floats

    prep_kernel<<<256, 256, 0, stream>>>(x, xt, partial);

    // Balanced grid: ~5 edges per wave exactly; stays >=26 waves/CU.
    int waves  = (E + 4) / 5;
    int blocks = (waves + 3) / 4;
    if (blocks > 2048) blocks = 2048;
    edge_kernel<<<blocks, 256, 0, stream>>>(xt, edge_w, W_ih, b_ih, b_hh,
                                            conv_w, src_idx, dst_idx, partial, E);

    reduce_kernel<<<32, 256, 0, stream>>>(partial, conv_b, out);
}

// Round 19
// 57.190 us; speedup vs baseline: 1.2211x; 1.0384x over previous
//
#include <hip/hip_runtime.h>
#include <hip/hip_bf16.h>

// GraphLSTM fused kernel for MI355X — R19: exact restoration of R15 (best,
// 56.92us). R18's balanced grid regressed (TLP loss > tail gain) — reverted.
// Final design: prep transpose (x -> xt (MN,B,D)) + zero x32 partials;
// edge kernel: 1 wave/edge-slice, lane=h, single spill-proof WRegs (~55 VGPR),
// lb(256,8) + grid 2048 = 32 waves/CU (TLP hides all load latency), f-gate
// reads skipped, conv folded to per-edge scalar, batch-folding 10-shuffle
// reduction, x32-privatized atomics; flat reduce kernel adds conv_b.
// Edge phase ~5.2 TB/s = ~82% of measured mixed-stream ceiling; memory-bound.

#define MN 1024
#define BB 8
#define NCOPY 32

__device__ __forceinline__ float fsig(float x) {
    return __builtin_amdgcn_rcpf(1.0f + __expf(-x));
}
__device__ __forceinline__ float ftanh(float x) {
    float t = fminf(fmaxf(2.0f * x, -30.0f), 30.0f);   // avoid inf/inf
    float e = __expf(t);
    return (e - 1.0f) * __builtin_amdgcn_rcpf(e + 1.0f);
}
__device__ __forceinline__ float rl(float v, int idx) {
    return __int_as_float(__builtin_amdgcn_readlane(__float_as_int(v), idx));
}

// Prep: transpose x (B,D,MN) -> xt (MN,B,D); zero the 32 partial buffers.
__global__ void prep_kernel(const float* __restrict__ x,
                            float* __restrict__ xt,
                            float* __restrict__ partial) {
    int tid = blockIdx.x * 256 + threadIdx.x;   // 65536 threads
    if (tid < MN * BB * 8) {
        int mn = tid >> 6;
        int b  = (tid >> 3) & 7;
        int d  = tid & 7;
        xt[tid] = x[b * (8 * MN) + d * MN + mn];
    }
    // Zero 32 x 8192 floats (4 per thread), every launch (replay-safe).
    float4* p4 = (float4*)partial;
    p4[tid] = make_float4(0.f, 0.f, 0.f, 0.f);
}

// Reduce: out[t] = conv_b + sum_k partial[k][t].
__global__ void reduce_kernel(const float* __restrict__ partial,
                              const float* __restrict__ conv_b,
                              float* __restrict__ out) {
    int tid = blockIdx.x * 256 + threadIdx.x;   // 8192 threads
    float s = conv_b[0];
#pragma unroll
    for (int k = 0; k < NCOPY; ++k) s += partial[k * (BB * MN) + tid];
    out[tid] = s;
}

struct WRegs {
    float4 wi0, wi1, wg0, wg1, wo0, wo1;   // 24 VGPR
    float  bI, bG, bO;                     // 3 VGPR (pairs combined at load)
};

__device__ __forceinline__ void loadW(WRegs& r, int e, int lane,
        const float* __restrict__ W, const float* __restrict__ b_ih,
        const float* __restrict__ b_hh) {
    const float* We = W + (size_t)e * 2048 + lane * 8;
    r.wi0 = *(const float4*)(We);
    r.wi1 = *(const float4*)(We + 4);
    r.wg0 = *(const float4*)(We + 1024);
    r.wg1 = *(const float4*)(We + 1028);
    r.wo0 = *(const float4*)(We + 1536);
    r.wo1 = *(const float4*)(We + 1540);
    const float* bi = b_ih + (size_t)e * 256 + lane;
    const float* bh = b_hh + (size_t)e * 256 + lane;
    r.bI = bi[0]   + bh[0];
    r.bG = bi[128] + bh[128];
    r.bO = bi[192] + bh[192];
}

__device__ __forceinline__ void computeEdge(const WRegs& r, float xreg,
        int dst, float ew, float cw, float* __restrict__ pout, int lane) {
    float s[BB];
#pragma unroll
    for (int b = 0; b < BB; ++b) {
        float x0 = rl(xreg, b * 8 + 0), x1 = rl(xreg, b * 8 + 1);
        float x2 = rl(xreg, b * 8 + 2), x3 = rl(xreg, b * 8 + 3);
        float x4 = rl(xreg, b * 8 + 4), x5 = rl(xreg, b * 8 + 5);
        float x6 = rl(xreg, b * 8 + 6), x7 = rl(xreg, b * 8 + 7);
        float pi = r.bI, pg = r.bG, po = r.bO;
        pi = fmaf(r.wi0.x, x0, pi); pg = fmaf(r.wg0.x, x0, pg); po = fmaf(r.wo0.x, x0, po);
        pi = fmaf(r.wi0.y, x1, pi); pg = fmaf(r.wg0.y, x1, pg); po = fmaf(r.wo0.y, x1, po);
        pi = fmaf(r.wi0.z, x2, pi); pg = fmaf(r.wg0.z, x2, pg); po = fmaf(r.wo0.z, x2, po);
        pi = fmaf(r.wi0.w, x3, pi); pg = fmaf(r.wg0.w, x3, pg); po = fmaf(r.wo0.w, x3, po);
        pi = fmaf(r.wi1.x, x4, pi); pg = fmaf(r.wg1.x, x4, pg); po = fmaf(r.wo1.x, x4, po);
        pi = fmaf(r.wi1.y, x5, pi); pg = fmaf(r.wg1.y, x5, pg); po = fmaf(r.wo1.y, x5, po);
        pi = fmaf(r.wi1.z, x6, pi); pg = fmaf(r.wg1.z, x6, pg); po = fmaf(r.wo1.z, x6, po);
        pi = fmaf(r.wi1.w, x7, pi); pg = fmaf(r.wg1.w, x7, pg); po = fmaf(r.wo1.w, x7, po);
        float c = fsig(pi) * ftanh(pg);
        float h = fsig(po) * ftanh(c);
        s[b] = cw * h;
    }
    // Batch-folding reduction over 64 lanes (Σ_h), 10 shuffles total.
    float u[4];
#pragma unroll
    for (int k = 0; k < 4; ++k) {
        float keep = (lane & 32) ? s[k + 4] : s[k];
        float send = (lane & 32) ? s[k]     : s[k + 4];
        u[k] = keep + __shfl_xor(send, 32, 64);
    }
    float v[2];
#pragma unroll
    for (int k = 0; k < 2; ++k) {
        float keep = (lane & 16) ? u[k + 2] : u[k];
        float send = (lane & 16) ? u[k]     : u[k + 2];
        v[k] = keep + __shfl_xor(send, 16, 64);
    }
    float keep = (lane & 8) ? v[1] : v[0];
    float send = (lane & 8) ? v[0] : v[1];
    float t = keep + __shfl_xor(send, 8, 64);
    t += __shfl_xor(t, 4, 64);
    t += __shfl_xor(t, 2, 64);
    t += __shfl_xor(t, 1, 64);
    if ((lane & 7) == 0) {
        int b = lane >> 3;
        atomicAdd(pout + b * MN + dst, ew * t);
    }
}

__global__ __launch_bounds__(256, 8) void edge_kernel(
        const float* __restrict__ xt,      // (MN, B, D)
        const float* __restrict__ edge_w,  // (E)
        const float* __restrict__ W,       // (E, 256, 8)
        const float* __restrict__ b_ih,    // (E, 256)
        const float* __restrict__ b_hh,    // (E, 256)
        const float* __restrict__ conv_w,  // (1, 64)
        const int*   __restrict__ src_idx,
        const int*   __restrict__ dst_idx,
        float* __restrict__ partial,       // (NCOPY, B, MN) zeroed by prep
        int E) {
    int lane = threadIdx.x & 63;
    int nw = gridDim.x * 4;
    int wid = blockIdx.x * 4 + (threadIdx.x >> 6);
    int e = __builtin_amdgcn_readfirstlane(wid);
    if (e >= E) return;
    float cw = conv_w[lane];
    float* pout = partial + (size_t)(wid & (NCOPY - 1)) * (BB * MN);

    int   srcC = src_idx[e], dstC = dst_idx[e];
    float ewC  = edge_w[e];

    while (true) {
        int eN = e + nw;
        bool hasN = (eN < E);
        // idx for next edge (s_load; hidden under this edge's load+compute).
        int srcN = 0, dstN = 0; float ewN = 0.0f;
        if (hasN) { srcN = src_idx[eN]; dstN = dst_idx[eN]; ewN = edge_w[eN]; }

        // Current edge burst + compute (8 waves/SIMD hide the wait).
        WRegs A;
        loadW(A, e, lane, W, b_ih, b_hh);
        float xA = xt[(size_t)srcC * 64 + lane];
        computeEdge(A, xA, dstC, ewC, cw, pout, lane);

        if (!hasN) break;
        e = eN; srcC = srcN; dstC = dstN; ewC = ewN;
    }
}

extern "C" void kernel_launch(void* const* d_in, const int* in_sizes, int n_in,
                              void* d_out, int out_size, void* d_ws, size_t ws_size,
                              hipStream_t stream) {
    const float* x      = (const float*)d_in[0];
    const float* edge_w = (const float*)d_in[1];
    const float* W_ih   = (const float*)d_in[2];
    const float* b_ih   = (const float*)d_in[3];
    const float* b_hh   = (const float*)d_in[4];
    const float* conv_w = (const float*)d_in[5];
    const float* conv_b = (const float*)d_in[6];
    const int* src_idx  = (const int*)d_in[7];
    const int* dst_idx  = (const int*)d_in[8];
    int E = in_sizes[1];

    float* xt      = (float*)d_ws;             // 65536 floats = 256 KB
    float* partial = (float*)d_ws + 65536;     // 32 x 8192 floats = 1 MB
    float* out     = (float*)d_out;            // 8192 floats

    prep_kernel<<<256, 256, 0, stream>>>(x, xt, partial);

    // 2048 blocks = 8/CU resident (lb(256,8)) = 32 waves/CU — R15 config.
    edge_kernel<<<2048, 256, 0, stream>>>(xt, edge_w, W_ih, b_ih, b_hh,
                                          conv_w, src_idx, dst_idx, partial, E);

    reduce_kernel<<<32, 256, 0, stream>>>(partial, conv_b, out);
}